// Round 2
// baseline (495.824 us; speedup 1.0000x reference)
//
#include <hip/hip_runtime.h>
#include <hip/hip_bf16.h>

// RNN-T Joiner. N=8 T=512 U=64 J=512 V=500 (padded to 512).
// ws: enc_p f32 [4096,512] (8MB) | dec_p f32 [512,512] (1MB) | wimg bf16 swizzled [8kt][64KB]
// joiner: BM=128 (2t x 64u), BN=512 (all V), BK=64, 8 waves (2x4), wave tile 64x128.
// B staged via global_load_lds from pre-swizzled image; A computed (tanh) once.
// MFMA operands swapped so epilogue is float4-per-lane aligned stores.

typedef __attribute__((ext_vector_type(4))) float f32x4;
typedef __attribute__((ext_vector_type(8))) short s16x8;

static __device__ __forceinline__ unsigned short f2bf(float x) {
    union { float f; unsigned u; } v; v.f = x;
    return (unsigned short)((v.u + 0x7FFFu + ((v.u >> 16) & 1u)) >> 16);  // RNE
}

static __device__ __forceinline__ float fast_tanh(float x) {
    // tanh(x) = 1 - 2/(exp(2x)+1); exact at +-inf; err << bf16 rounding
    float e = __expf(2.0f * x);
    float r = __builtin_amdgcn_rcpf(e + 1.0f);
    return __builtin_fmaf(-2.0f, r, 1.0f);
}

#define GLOAD16(gsrc, ldst)                                                  \
    __builtin_amdgcn_global_load_lds(                                        \
        (const __attribute__((address_space(1))) unsigned int*)(gsrc),       \
        (__attribute__((address_space(3))) unsigned int*)(ldst), 16, 0, 0)

// ---------------- projection GEMM (unchanged from passing R1) ----------------
__global__ __launch_bounds__(256) void proj_gemm(
    const float* __restrict__ A, const float* __restrict__ W,
    const float* __restrict__ b, float* __restrict__ C)
{
    __shared__ unsigned short As[128 * 64];
    __shared__ unsigned short Bs[128 * 64];
    const int mt = blockIdx.x, jt = blockIdx.y;
    const int tid = threadIdx.x;
    const int lane = tid & 63, wid = tid >> 6;
    const int wm = wid >> 1, wn = wid & 1;

    f32x4 acc[4][4];
    const f32x4 zero = {0.f, 0.f, 0.f, 0.f};
    #pragma unroll
    for (int i = 0; i < 4; ++i)
        #pragma unroll
        for (int j = 0; j < 4; ++j) acc[i][j] = zero;

    const int c8 = (tid & 7) * 8;
    const int rbase = tid >> 3;

    for (int kt = 0; kt < 8; ++kt) {
        __syncthreads();
        #pragma unroll
        for (int p = 0; p < 4; ++p) {
            int r = p * 32 + rbase;
            int byte = (r * 128 + c8 * 2) ^ ((r & 7) << 4);
            {
                const float* s = A + (size_t)(mt * 128 + r) * 512 + kt * 64 + c8;
                f32x4 v0 = *(const f32x4*)s, v1 = *(const f32x4*)(s + 4);
                s16x8 pk;
                pk[0] = (short)f2bf(v0[0]); pk[1] = (short)f2bf(v0[1]);
                pk[2] = (short)f2bf(v0[2]); pk[3] = (short)f2bf(v0[3]);
                pk[4] = (short)f2bf(v1[0]); pk[5] = (short)f2bf(v1[1]);
                pk[6] = (short)f2bf(v1[2]); pk[7] = (short)f2bf(v1[3]);
                *(s16x8*)((char*)As + byte) = pk;
            }
            {
                const float* s = W + (size_t)(jt * 128 + r) * 512 + kt * 64 + c8;
                f32x4 v0 = *(const f32x4*)s, v1 = *(const f32x4*)(s + 4);
                s16x8 pk;
                pk[0] = (short)f2bf(v0[0]); pk[1] = (short)f2bf(v0[1]);
                pk[2] = (short)f2bf(v0[2]); pk[3] = (short)f2bf(v0[3]);
                pk[4] = (short)f2bf(v1[0]); pk[5] = (short)f2bf(v1[1]);
                pk[6] = (short)f2bf(v1[2]); pk[7] = (short)f2bf(v1[3]);
                *(s16x8*)((char*)Bs + byte) = pk;
            }
        }
        __syncthreads();
        #pragma unroll
        for (int kk = 0; kk < 2; ++kk) {
            s16x8 af[4], bfr[4];
            #pragma unroll
            for (int mi = 0; mi < 4; ++mi) {
                int row = wm * 64 + mi * 16 + (lane & 15);
                int byte = (row * 128 + kk * 64 + ((lane >> 4) * 16)) ^ ((row & 7) << 4);
                af[mi] = *(const s16x8*)((const char*)As + byte);
            }
            #pragma unroll
            for (int ni = 0; ni < 4; ++ni) {
                int row = wn * 64 + ni * 16 + (lane & 15);
                int byte = (row * 128 + kk * 64 + ((lane >> 4) * 16)) ^ ((row & 7) << 4);
                bfr[ni] = *(const s16x8*)((const char*)Bs + byte);
            }
            #pragma unroll
            for (int mi = 0; mi < 4; ++mi)
                #pragma unroll
                for (int ni = 0; ni < 4; ++ni)
                    acc[mi][ni] = __builtin_amdgcn_mfma_f32_16x16x32_bf16(
                        af[mi], bfr[ni], acc[mi][ni], 0, 0, 0);
        }
    }

    #pragma unroll
    for (int ni = 0; ni < 4; ++ni) {
        int col = jt * 128 + wn * 64 + ni * 16 + (lane & 15);
        float bias = b[col];
        #pragma unroll
        for (int mi = 0; mi < 4; ++mi) {
            int row0 = mt * 128 + wm * 64 + mi * 16 + ((lane >> 4) << 2);
            #pragma unroll
            for (int j = 0; j < 4; ++j)
                C[(size_t)(row0 + j) * 512 + col] = acc[mi][ni][j] + bias;
        }
    }
}

// ---------------- W_out -> bf16, pre-swizzled LDS image ----------------
// img[kt][byte], byte = (v*128 + c*2) ^ ((v&7)<<4), v in [0,512) (>=500 zero), c in [0,64)
__global__ __launch_bounds__(256) void conv_wout(
    const float* __restrict__ W, unsigned short* __restrict__ img)
{
    int tid = blockIdx.x * 256 + threadIdx.x;   // 32768 total: kt(8) x v(512) x chunk(8)
    int cc = tid & 7, v = (tid >> 3) & 511, kt = tid >> 12;
    int c8 = cc * 8;
    s16x8 pk = {0, 0, 0, 0, 0, 0, 0, 0};
    if (v < 500) {
        const float* s = W + (size_t)v * 512 + kt * 64 + c8;
        f32x4 a = *(const f32x4*)s, b = *(const f32x4*)(s + 4);
        pk[0] = (short)f2bf(a[0]); pk[1] = (short)f2bf(a[1]);
        pk[2] = (short)f2bf(a[2]); pk[3] = (short)f2bf(a[3]);
        pk[4] = (short)f2bf(b[0]); pk[5] = (short)f2bf(b[1]);
        pk[6] = (short)f2bf(b[2]); pk[7] = (short)f2bf(b[3]);
    }
    unsigned byte = (unsigned)(v * 128 + c8 * 2) ^ ((unsigned)(v & 7) << 4);
    *(s16x8*)((char*)img + (size_t)kt * 65536 + byte) = pk;
}

// ---------------- fused tanh + vocab GEMM ----------------
__global__ __launch_bounds__(512, 2) void joiner_main(
    const float* __restrict__ enc, const float* __restrict__ dec,
    const unsigned short* __restrict__ Wimg, const float* __restrict__ bout,
    float* __restrict__ out)
{
    __shared__ unsigned short As[128 * 64];   // 16 KB
    __shared__ unsigned short Bs[512 * 64];   // 64 KB
    const int bid = blockIdx.x;
    const int mt = bid & 255, n = bid >> 8;
    const int tid = threadIdx.x, lane = tid & 63, wid = tid >> 6;
    const int wm = wid >> 2, wn = wid & 3;     // 2 x 4 waves

    const float* encN = enc + (size_t)n * (512 * 512);
    const float* decN = dec + (size_t)n * (64 * 512);

    f32x4 acc[4][8];
    const f32x4 zero = {0.f, 0.f, 0.f, 0.f};
    #pragma unroll
    for (int i = 0; i < 4; ++i)
        #pragma unroll
        for (int j = 0; j < 8; ++j) acc[i][j] = zero;

    // A staging: thread -> row r = tid>>2 (0..127), k-offset (tid&3)*16
    const int r = tid >> 2;
    const int k16 = (tid & 3) * 16;
    const int tt = r >> 6, u = r & 63;
    const float* erow = encN + (size_t)(mt * 2 + tt) * 512 + k16;
    const float* drow = decN + (size_t)u * 512 + k16;
    const unsigned abyte0 = ((unsigned)(r * 128 + k16 * 2)) ^ ((unsigned)(r & 7) << 4);
    const unsigned abyte1 = ((unsigned)(r * 128 + k16 * 2 + 16)) ^ ((unsigned)(r & 7) << 4);
    // B staging: wave wid copies bytes [wid*8K, wid*8K+8K) in 8 calls of 1KB
    const char* bsrc0 = (const char*)Wimg + (size_t)wid * 8192 + (size_t)lane * 16;
    char* bdst0 = (char*)Bs + wid * 8192;

    for (int kt = 0; kt < 8; ++kt) {
        __syncthreads();
        // ---- stage A: tanh(enc+dec) -> bf16, swizzled ds_write ----
        {
            const float* e = erow + kt * 64;
            const float* d = drow + kt * 64;
            f32x4 e0 = *(const f32x4*)e,       e1 = *(const f32x4*)(e + 4);
            f32x4 e2 = *(const f32x4*)(e + 8), e3 = *(const f32x4*)(e + 12);
            f32x4 d0 = *(const f32x4*)d,       d1 = *(const f32x4*)(d + 4);
            f32x4 d2 = *(const f32x4*)(d + 8), d3 = *(const f32x4*)(d + 12);
            s16x8 p0, p1;
            p0[0] = (short)f2bf(fast_tanh(e0[0] + d0[0]));
            p0[1] = (short)f2bf(fast_tanh(e0[1] + d0[1]));
            p0[2] = (short)f2bf(fast_tanh(e0[2] + d0[2]));
            p0[3] = (short)f2bf(fast_tanh(e0[3] + d0[3]));
            p0[4] = (short)f2bf(fast_tanh(e1[0] + d1[0]));
            p0[5] = (short)f2bf(fast_tanh(e1[1] + d1[1]));
            p0[6] = (short)f2bf(fast_tanh(e1[2] + d1[2]));
            p0[7] = (short)f2bf(fast_tanh(e1[3] + d1[3]));
            p1[0] = (short)f2bf(fast_tanh(e2[0] + d2[0]));
            p1[1] = (short)f2bf(fast_tanh(e2[1] + d2[1]));
            p1[2] = (short)f2bf(fast_tanh(e2[2] + d2[2]));
            p1[3] = (short)f2bf(fast_tanh(e2[3] + d2[3]));
            p1[4] = (short)f2bf(fast_tanh(e3[0] + d3[0]));
            p1[5] = (short)f2bf(fast_tanh(e3[1] + d3[1]));
            p1[6] = (short)f2bf(fast_tanh(e3[2] + d3[2]));
            p1[7] = (short)f2bf(fast_tanh(e3[3] + d3[3]));
            *(s16x8*)((char*)As + abyte0) = p0;
            *(s16x8*)((char*)As + abyte1) = p1;
        }
        // ---- stage B: async copy of pre-swizzled image (no VALU) ----
        {
            const char* g = bsrc0 + (size_t)kt * 65536;
            #pragma unroll
            for (int i = 0; i < 8; ++i)
                GLOAD16(g + i * 1024, bdst0 + i * 1024);
        }
        __syncthreads();  // drains lgkm (A writes) + vmcnt (B gload_lds)
        // ---- MFMA: operands swapped -> acc lane holds 4 consecutive v ----
        #pragma unroll
        for (int kk = 0; kk < 2; ++kk) {
            s16x8 af[4], bfr[8];
            #pragma unroll
            for (int mi = 0; mi < 4; ++mi) {
                int row = wm * 64 + mi * 16 + (lane & 15);
                int byte = (row * 128 + kk * 64 + ((lane >> 4) * 16)) ^ ((row & 7) << 4);
                af[mi] = *(const s16x8*)((const char*)As + byte);
            }
            #pragma unroll
            for (int ni = 0; ni < 8; ++ni) {
                int row = wn * 128 + ni * 16 + (lane & 15);
                int byte = (row * 128 + kk * 64 + ((lane >> 4) * 16)) ^ ((row & 7) << 4);
                bfr[ni] = *(const s16x8*)((const char*)Bs + byte);
            }
            #pragma unroll
            for (int mi = 0; mi < 4; ++mi)
                #pragma unroll
                for (int ni = 0; ni < 8; ++ni)
                    acc[mi][ni] = __builtin_amdgcn_mfma_f32_16x16x32_bf16(
                        bfr[ni], af[mi], acc[mi][ni], 0, 0, 0);
        }
    }

    // ---- epilogue: lane holds m = lane&15 (+16mi), v4 = ni*16 + 4*(lane>>4) ----
    const int g4 = (lane >> 4) << 2, c = lane & 15;
    const size_t mg = (size_t)n * 32768 + (size_t)mt * 128;
    #pragma unroll
    for (int ni = 0; ni < 8; ++ni) {
        int v4 = wn * 128 + ni * 16 + g4;
        if (v4 < 500) {
            f32x4 bias = *(const f32x4*)(bout + v4);
            #pragma unroll
            for (int mi = 0; mi < 4; ++mi) {
                int m = wm * 64 + mi * 16 + c;
                f32x4 o;
                o[0] = acc[mi][ni][0] + bias[0];
                o[1] = acc[mi][ni][1] + bias[1];
                o[2] = acc[mi][ni][2] + bias[2];
                o[3] = acc[mi][ni][3] + bias[3];
                __builtin_nontemporal_store(o, (f32x4*)(out + (mg + m) * 500 + v4));
            }
        }
    }
}

extern "C" void kernel_launch(void* const* d_in, const int* in_sizes, int n_in,
                              void* d_out, int out_size, void* d_ws, size_t ws_size,
                              hipStream_t stream) {
    const float* encoder_out = (const float*)d_in[0];  // [8,512,512]
    const float* decoder_out = (const float*)d_in[1];  // [8,64,512]
    const float* W_enc = (const float*)d_in[2];
    const float* b_enc = (const float*)d_in[3];
    const float* W_dec = (const float*)d_in[4];
    const float* b_dec = (const float*)d_in[5];
    const float* W_out = (const float*)d_in[6];        // [500,512]
    const float* b_out = (const float*)d_in[7];        // [500]
    float* out = (float*)d_out;                        // [8,512,64,500]

    float* enc_p = (float*)d_ws;                                   // 8 MB
    float* dec_p = enc_p + (size_t)8 * 512 * 512;                  // 1 MB
    unsigned short* wimg = (unsigned short*)(dec_p + (size_t)8 * 64 * 512);  // 512 KB

    conv_wout<<<dim3(128), 256, 0, stream>>>(W_out, wimg);
    proj_gemm<<<dim3(32, 4), 256, 0, stream>>>(encoder_out, W_enc, b_enc, enc_p);
    proj_gemm<<<dim3(4, 4), 256, 0, stream>>>(decoder_out, W_dec, b_dec, dec_p);
    joiner_main<<<dim3(2048), 512, 0, stream>>>(enc_p, dec_p, wimg, b_out, out);
}

// Round 3
// 296.639 us; speedup vs baseline: 1.6715x; 1.6715x over previous
//
#include <hip/hip_runtime.h>
#include <hip/hip_bf16.h>

// RNN-T Joiner. N=8 T=512 U=64 J=512 V=500 (padded to 512).
// ws: enc_p f32 [4096,512] (8MB) | dec_p f32 [512,512] (1MB) | wimg bf16 swizzled [8kt][64KB]
// joiner: BM=128 (2t x 64u), BN=512 (all V), BK=64, 8 waves (2x4), wave tile 64x128.
// Epilogue: LDS-transpose per 32-row quarter -> fully coalesced contiguous f32x4 streams.

typedef __attribute__((ext_vector_type(4))) float f32x4;
typedef __attribute__((ext_vector_type(8))) short s16x8;

static __device__ __forceinline__ unsigned short f2bf(float x) {
    union { float f; unsigned u; } v; v.f = x;
    return (unsigned short)((v.u + 0x7FFFu + ((v.u >> 16) & 1u)) >> 16);  // RNE
}

static __device__ __forceinline__ float fast_tanh(float x) {
    float e = __expf(2.0f * x);
    float r = __builtin_amdgcn_rcpf(e + 1.0f);
    return __builtin_fmaf(-2.0f, r, 1.0f);
}

#define GLOAD16(gsrc, ldst)                                                  \
    __builtin_amdgcn_global_load_lds(                                        \
        (const __attribute__((address_space(1))) unsigned int*)(gsrc),       \
        (__attribute__((address_space(3))) unsigned int*)(ldst), 16, 0, 0)

// ---------------- projection GEMM (unchanged, verified) ----------------
__global__ __launch_bounds__(256) void proj_gemm(
    const float* __restrict__ A, const float* __restrict__ W,
    const float* __restrict__ b, float* __restrict__ C)
{
    __shared__ unsigned short As[128 * 64];
    __shared__ unsigned short Bs[128 * 64];
    const int mt = blockIdx.x, jt = blockIdx.y;
    const int tid = threadIdx.x;
    const int lane = tid & 63, wid = tid >> 6;
    const int wm = wid >> 1, wn = wid & 1;

    f32x4 acc[4][4];
    const f32x4 zero = {0.f, 0.f, 0.f, 0.f};
    #pragma unroll
    for (int i = 0; i < 4; ++i)
        #pragma unroll
        for (int j = 0; j < 4; ++j) acc[i][j] = zero;

    const int c8 = (tid & 7) * 8;
    const int rbase = tid >> 3;

    for (int kt = 0; kt < 8; ++kt) {
        __syncthreads();
        #pragma unroll
        for (int p = 0; p < 4; ++p) {
            int r = p * 32 + rbase;
            int byte = (r * 128 + c8 * 2) ^ ((r & 7) << 4);
            {
                const float* s = A + (size_t)(mt * 128 + r) * 512 + kt * 64 + c8;
                f32x4 v0 = *(const f32x4*)s, v1 = *(const f32x4*)(s + 4);
                s16x8 pk;
                pk[0] = (short)f2bf(v0[0]); pk[1] = (short)f2bf(v0[1]);
                pk[2] = (short)f2bf(v0[2]); pk[3] = (short)f2bf(v0[3]);
                pk[4] = (short)f2bf(v1[0]); pk[5] = (short)f2bf(v1[1]);
                pk[6] = (short)f2bf(v1[2]); pk[7] = (short)f2bf(v1[3]);
                *(s16x8*)((char*)As + byte) = pk;
            }
            {
                const float* s = W + (size_t)(jt * 128 + r) * 512 + kt * 64 + c8;
                f32x4 v0 = *(const f32x4*)s, v1 = *(const f32x4*)(s + 4);
                s16x8 pk;
                pk[0] = (short)f2bf(v0[0]); pk[1] = (short)f2bf(v0[1]);
                pk[2] = (short)f2bf(v0[2]); pk[3] = (short)f2bf(v0[3]);
                pk[4] = (short)f2bf(v1[0]); pk[5] = (short)f2bf(v1[1]);
                pk[6] = (short)f2bf(v1[2]); pk[7] = (short)f2bf(v1[3]);
                *(s16x8*)((char*)Bs + byte) = pk;
            }
        }
        __syncthreads();
        #pragma unroll
        for (int kk = 0; kk < 2; ++kk) {
            s16x8 af[4], bfr[4];
            #pragma unroll
            for (int mi = 0; mi < 4; ++mi) {
                int row = wm * 64 + mi * 16 + (lane & 15);
                int byte = (row * 128 + kk * 64 + ((lane >> 4) * 16)) ^ ((row & 7) << 4);
                af[mi] = *(const s16x8*)((const char*)As + byte);
            }
            #pragma unroll
            for (int ni = 0; ni < 4; ++ni) {
                int row = wn * 64 + ni * 16 + (lane & 15);
                int byte = (row * 128 + kk * 64 + ((lane >> 4) * 16)) ^ ((row & 7) << 4);
                bfr[ni] = *(const s16x8*)((const char*)Bs + byte);
            }
            #pragma unroll
            for (int mi = 0; mi < 4; ++mi)
                #pragma unroll
                for (int ni = 0; ni < 4; ++ni)
                    acc[mi][ni] = __builtin_amdgcn_mfma_f32_16x16x32_bf16(
                        af[mi], bfr[ni], acc[mi][ni], 0, 0, 0);
        }
    }

    #pragma unroll
    for (int ni = 0; ni < 4; ++ni) {
        int col = jt * 128 + wn * 64 + ni * 16 + (lane & 15);
        float bias = b[col];
        #pragma unroll
        for (int mi = 0; mi < 4; ++mi) {
            int row0 = mt * 128 + wm * 64 + mi * 16 + ((lane >> 4) << 2);
            #pragma unroll
            for (int j = 0; j < 4; ++j)
                C[(size_t)(row0 + j) * 512 + col] = acc[mi][ni][j] + bias;
        }
    }
}

// ---------------- W_out -> bf16, pre-swizzled LDS image ----------------
__global__ __launch_bounds__(256) void conv_wout(
    const float* __restrict__ W, unsigned short* __restrict__ img)
{
    int tid = blockIdx.x * 256 + threadIdx.x;   // kt(8) x v(512) x chunk(8)
    int cc = tid & 7, v = (tid >> 3) & 511, kt = tid >> 12;
    int c8 = cc * 8;
    s16x8 pk = {0, 0, 0, 0, 0, 0, 0, 0};
    if (v < 500) {
        const float* s = W + (size_t)v * 512 + kt * 64 + c8;
        f32x4 a = *(const f32x4*)s, b = *(const f32x4*)(s + 4);
        pk[0] = (short)f2bf(a[0]); pk[1] = (short)f2bf(a[1]);
        pk[2] = (short)f2bf(a[2]); pk[3] = (short)f2bf(a[3]);
        pk[4] = (short)f2bf(b[0]); pk[5] = (short)f2bf(b[1]);
        pk[6] = (short)f2bf(b[2]); pk[7] = (short)f2bf(b[3]);
    }
    unsigned byte = (unsigned)(v * 128 + c8 * 2) ^ ((unsigned)(v & 7) << 4);
    *(s16x8*)((char*)img + (size_t)kt * 65536 + byte) = pk;
}

// ---------------- fused tanh + vocab GEMM ----------------
__global__ __launch_bounds__(512, 2) void joiner_main(
    const float* __restrict__ enc, const float* __restrict__ dec,
    const unsigned short* __restrict__ Wimg, const float* __restrict__ bout,
    float* __restrict__ out)
{
    __shared__ __align__(16) char raw[81920];           // 80 KB
    unsigned short* As = (unsigned short*)raw;          // 16 KB
    unsigned short* Bs = (unsigned short*)(raw + 16384);// 64 KB
    float* ep = (float*)raw;                            // epilogue [32][516] f32 = 66 KB

    const int bid = blockIdx.x;
    const int mt = bid & 255, n = bid >> 8;
    const int tid = threadIdx.x, lane = tid & 63, wid = tid >> 6;
    const int wm = wid >> 2, wn = wid & 3;     // 2 x 4 waves

    const float* encN = enc + (size_t)n * (512 * 512);
    const float* decN = dec + (size_t)n * (64 * 512);

    f32x4 acc[4][8];
    const f32x4 zero = {0.f, 0.f, 0.f, 0.f};
    #pragma unroll
    for (int i = 0; i < 4; ++i)
        #pragma unroll
        for (int j = 0; j < 8; ++j) acc[i][j] = zero;

    // A staging: thread -> row r = tid>>2 (0..127), k-offset (tid&3)*16
    const int r = tid >> 2;
    const int k16 = (tid & 3) * 16;
    const int tt = r >> 6, u = r & 63;
    const float* erow = encN + (size_t)(mt * 2 + tt) * 512 + k16;
    const float* drow = decN + (size_t)u * 512 + k16;
    const unsigned abyte0 = ((unsigned)(r * 128 + k16 * 2)) ^ ((unsigned)(r & 7) << 4);
    const unsigned abyte1 = ((unsigned)(r * 128 + k16 * 2 + 16)) ^ ((unsigned)(r & 7) << 4);
    const char* bsrc0 = (const char*)Wimg + (size_t)wid * 8192 + (size_t)lane * 16;
    char* bdst0 = (char*)Bs + wid * 8192;

    // software-prefetched A operands (next kt loads overlap MFMA phase)
    f32x4 ee[4], dd[4];
    {
        const float* e_ = erow; const float* d_ = drow;
        ee[0] = *(const f32x4*)e_;        ee[1] = *(const f32x4*)(e_ + 4);
        ee[2] = *(const f32x4*)(e_ + 8);  ee[3] = *(const f32x4*)(e_ + 12);
        dd[0] = *(const f32x4*)d_;        dd[1] = *(const f32x4*)(d_ + 4);
        dd[2] = *(const f32x4*)(d_ + 8);  dd[3] = *(const f32x4*)(d_ + 12);
    }

    for (int kt = 0; kt < 8; ++kt) {
        __syncthreads();
        // ---- stage A: tanh(enc+dec) -> bf16, swizzled ds_write ----
        {
            s16x8 p0, p1;
            p0[0] = (short)f2bf(fast_tanh(ee[0][0] + dd[0][0]));
            p0[1] = (short)f2bf(fast_tanh(ee[0][1] + dd[0][1]));
            p0[2] = (short)f2bf(fast_tanh(ee[0][2] + dd[0][2]));
            p0[3] = (short)f2bf(fast_tanh(ee[0][3] + dd[0][3]));
            p0[4] = (short)f2bf(fast_tanh(ee[1][0] + dd[1][0]));
            p0[5] = (short)f2bf(fast_tanh(ee[1][1] + dd[1][1]));
            p0[6] = (short)f2bf(fast_tanh(ee[1][2] + dd[1][2]));
            p0[7] = (short)f2bf(fast_tanh(ee[1][3] + dd[1][3]));
            p1[0] = (short)f2bf(fast_tanh(ee[2][0] + dd[2][0]));
            p1[1] = (short)f2bf(fast_tanh(ee[2][1] + dd[2][1]));
            p1[2] = (short)f2bf(fast_tanh(ee[2][2] + dd[2][2]));
            p1[3] = (short)f2bf(fast_tanh(ee[2][3] + dd[2][3]));
            p1[4] = (short)f2bf(fast_tanh(ee[3][0] + dd[3][0]));
            p1[5] = (short)f2bf(fast_tanh(ee[3][1] + dd[3][1]));
            p1[6] = (short)f2bf(fast_tanh(ee[3][2] + dd[3][2]));
            p1[7] = (short)f2bf(fast_tanh(ee[3][3] + dd[3][3]));
            *(s16x8*)((char*)As + abyte0) = p0;
            *(s16x8*)((char*)As + abyte1) = p1;
        }
        // ---- stage B: async copy of pre-swizzled image (no VALU) ----
        {
            const char* g = bsrc0 + (size_t)kt * 65536;
            #pragma unroll
            for (int i = 0; i < 8; ++i)
                GLOAD16(g + i * 1024, bdst0 + i * 1024);
        }
        // ---- prefetch A for kt+1 (drains at the same barrier as B) ----
        if (kt < 7) {
            const float* e_ = erow + (kt + 1) * 64;
            const float* d_ = drow + (kt + 1) * 64;
            ee[0] = *(const f32x4*)e_;        ee[1] = *(const f32x4*)(e_ + 4);
            ee[2] = *(const f32x4*)(e_ + 8);  ee[3] = *(const f32x4*)(e_ + 12);
            dd[0] = *(const f32x4*)d_;        dd[1] = *(const f32x4*)(d_ + 4);
            dd[2] = *(const f32x4*)(d_ + 8);  dd[3] = *(const f32x4*)(d_ + 12);
        }
        __syncthreads();
        // ---- MFMA: operands swapped -> acc lane holds 4 consecutive v ----
        #pragma unroll
        for (int kk = 0; kk < 2; ++kk) {
            s16x8 af[4], bfr[8];
            #pragma unroll
            for (int mi = 0; mi < 4; ++mi) {
                int row = wm * 64 + mi * 16 + (lane & 15);
                int byte = (row * 128 + kk * 64 + ((lane >> 4) * 16)) ^ ((row & 7) << 4);
                af[mi] = *(const s16x8*)((const char*)As + byte);
            }
            #pragma unroll
            for (int ni = 0; ni < 8; ++ni) {
                int row = wn * 128 + ni * 16 + (lane & 15);
                int byte = (row * 128 + kk * 64 + ((lane >> 4) * 16)) ^ ((row & 7) << 4);
                bfr[ni] = *(const s16x8*)((const char*)Bs + byte);
            }
            #pragma unroll
            for (int mi = 0; mi < 4; ++mi)
                #pragma unroll
                for (int ni = 0; ni < 8; ++ni)
                    acc[mi][ni] = __builtin_amdgcn_mfma_f32_16x16x32_bf16(
                        bfr[ni], af[mi], acc[mi][ni], 0, 0, 0);
        }
    }

    // ---- epilogue: per 32-row quarter, LDS transpose -> contiguous streams ----
    // acc[mi][ni][j]: m = wm*64+mi*16+(lane&15), v = wn*128+ni*16+(lane>>4)*4+j
    const int g4 = (lane >> 4) << 2, c = lane & 15;
    const size_t slab = ((size_t)n * 32768 + (size_t)mt * 128) * 500;
    #pragma unroll
    for (int q = 0; q < 4; ++q) {
        __syncthreads();   // previous users of LDS done
        if (wm == (q >> 1)) {
            #pragma unroll
            for (int b = 0; b < 2; ++b) {
                const int mi = (q & 1) * 2 + b;
                const int lr = b * 16 + c;              // local row 0..31
                #pragma unroll
                for (int ni = 0; ni < 8; ++ni) {
                    int v4 = wn * 128 + ni * 16 + g4;
                    if (v4 < 500) {
                        f32x4 bias = *(const f32x4*)(bout + v4);
                        f32x4 o;
                        o[0] = acc[mi][ni][0] + bias[0];
                        o[1] = acc[mi][ni][1] + bias[1];
                        o[2] = acc[mi][ni][2] + bias[2];
                        o[3] = acc[mi][ni][3] + bias[3];
                        *(f32x4*)(ep + lr * 516 + v4) = o;
                    }
                }
            }
        }
        __syncthreads();
        const size_t qbase = slab + (size_t)q * (32 * 500);
        #pragma unroll
        for (int i = 0; i < 8; ++i) {
            int idx = i * 512 + tid;                    // f32x4 chunk id, 4000 total
            if (idx < 4000) {
                int rr = idx / 125;                     // 125 chunks per 500-f32 row
                int vi = (idx - rr * 125) * 4;
                f32x4 o = *(const f32x4*)(ep + rr * 516 + vi);
                __builtin_nontemporal_store(o, (f32x4*)(out + qbase + (size_t)idx * 4));
            }
        }
    }
}

extern "C" void kernel_launch(void* const* d_in, const int* in_sizes, int n_in,
                              void* d_out, int out_size, void* d_ws, size_t ws_size,
                              hipStream_t stream) {
    const float* encoder_out = (const float*)d_in[0];  // [8,512,512]
    const float* decoder_out = (const float*)d_in[1];  // [8,64,512]
    const float* W_enc = (const float*)d_in[2];
    const float* b_enc = (const float*)d_in[3];
    const float* W_dec = (const float*)d_in[4];
    const float* b_dec = (const float*)d_in[5];
    const float* W_out = (const float*)d_in[6];        // [500,512]
    const float* b_out = (const float*)d_in[7];        // [500]
    float* out = (float*)d_out;                        // [8,512,64,500]

    float* enc_p = (float*)d_ws;                                   // 8 MB
    float* dec_p = enc_p + (size_t)8 * 512 * 512;                  // 1 MB
    unsigned short* wimg = (unsigned short*)(dec_p + (size_t)8 * 64 * 512);  // 512 KB

    conv_wout<<<dim3(128), 256, 0, stream>>>(W_out, wimg);
    proj_gemm<<<dim3(32, 4), 256, 0, stream>>>(encoder_out, W_enc, b_enc, enc_p);
    proj_gemm<<<dim3(4, 4), 256, 0, stream>>>(decoder_out, W_dec, b_dec, dec_p);
    joiner_main<<<dim3(2048), 512, 0, stream>>>(enc_p, dec_p, wimg, b_out, out);
}